// Round 3
// baseline (1144.966 us; speedup 1.0000x reference)
//
#include <hip/hip_runtime.h>

#define N_VEC   32768      // 32*1024
#define K_CODES 4096
#define D_DIM   64
#define NELEM   2097152    // N_VEC * D_DIM

// ---- output layout (floats, concatenated in reference return order) ----
#define OUT0_OFF 0           // quantized_st  (2097152)
#define OUT1_OFF 2097152     // loss          (1)
#define OUT2_OFF 2097153     // indices       (32768)
#define OUT3_OFF 2129921     // new_weight    (262144)
#define OUT4_OFF 2392065     // ema_cs        (4096)
#define OUT5_OFF 2396161     // ema_es        (262144)

// ---- ws layout (byte offsets, 8-aligned) ----
#define WS_BNORM   0            // float[4096]       (16384 B)  np-exact ||w_k||^2
#define WS_COUNTS  16384        // int[4096]         (16384 B)
#define WS_SUMS    32768        // float[4096*64]    (1048576 B)
#define WS_LPART   1081344      // double[8192]      (65536 B)
#define WS_CSPART  1146880      // double[16]        (128 B)

// numpy pairwise_sum base case (n=64): 8 accumulators strided by 8,
// sequential adds, fixed combine tree. sq[] must be PRE-ROUNDED squares.
__device__ __forceinline__ float np_pairwise64(const float* sq) {
    float r0 = sq[0], r1 = sq[1], r2 = sq[2], r3 = sq[3];
    float r4 = sq[4], r5 = sq[5], r6 = sq[6], r7 = sq[7];
#pragma unroll
    for (int b = 8; b < 64; b += 8) {
        r0 = __fadd_rn(r0, sq[b + 0]); r1 = __fadd_rn(r1, sq[b + 1]);
        r2 = __fadd_rn(r2, sq[b + 2]); r3 = __fadd_rn(r3, sq[b + 3]);
        r4 = __fadd_rn(r4, sq[b + 4]); r5 = __fadd_rn(r5, sq[b + 5]);
        r6 = __fadd_rn(r6, sq[b + 6]); r7 = __fadd_rn(r7, sq[b + 7]);
    }
    return __fadd_rn(__fadd_rn(__fadd_rn(r0, r1), __fadd_rn(r2, r3)),
                     __fadd_rn(__fadd_rn(r4, r5), __fadd_rn(r6, r7)));
}

// -------- B_k = np.sum(w_k*w_k) with numpy fp32 semantics ----------------
__global__ void k_bnorm(const float* __restrict__ w, float* __restrict__ bn) {
    int k = blockIdx.x * 256 + threadIdx.x;
    const float* wr = w + k * D_DIM;
    float sq[64];
#pragma unroll
    for (int i = 0; i < 64; ++i) { float v = wr[i]; sq[i] = __fmul_rn(v, v); }
    bn[k] = np_pairwise64(sq);
}

// -------- scorer: bit-replicate np fp32 distances, argmin first-index ----
// 1 thread = 1 row n. 4 codewords in flight (4 independent FMA chains).
// d_nk = fl( fl(A_n + B_k) - 2*C_nk ), C_nk = ascending-d fp32 FMA chain.
#define CH4(acc, xc, wc)                                \
    acc = __fmaf_rn((xc).x, (wc).x, acc);               \
    acc = __fmaf_rn((xc).y, (wc).y, acc);               \
    acc = __fmaf_rn((xc).z, (wc).z, acc);               \
    acc = __fmaf_rn((xc).w, (wc).w, acc);

__global__ __launch_bounds__(256) void k_score(
    const float* __restrict__ x, const float* __restrict__ w,
    const float* __restrict__ bn, float* __restrict__ out_idx) {
    const int n = blockIdx.x * 256 + threadIdx.x;

    float4 xv[16];
    {
        const float4* xr = (const float4*)(x + (size_t)n * D_DIM);
#pragma unroll
        for (int i = 0; i < 16; ++i) xv[i] = xr[i];
    }
    // A_n: numpy-exact sum of pre-rounded squares
    float A;
    {
        float sq[64];
#pragma unroll
        for (int i = 0; i < 16; ++i) {
            sq[4*i+0] = __fmul_rn(xv[i].x, xv[i].x);
            sq[4*i+1] = __fmul_rn(xv[i].y, xv[i].y);
            sq[4*i+2] = __fmul_rn(xv[i].z, xv[i].z);
            sq[4*i+3] = __fmul_rn(xv[i].w, xv[i].w);
        }
        A = np_pairwise64(sq);
    }

    float bestd = 3.4e38f;
    int   besti = 0;
    for (int kb = 0; kb < K_CODES; kb += 4) {
        const float4* w0 = (const float4*)(w + (size_t)(kb + 0) * D_DIM);
        const float4* w1 = (const float4*)(w + (size_t)(kb + 1) * D_DIM);
        const float4* w2 = (const float4*)(w + (size_t)(kb + 2) * D_DIM);
        const float4* w3 = (const float4*)(w + (size_t)(kb + 3) * D_DIM);
        float a0 = 0.f, a1 = 0.f, a2 = 0.f, a3 = 0.f;
#pragma unroll
        for (int c = 0; c < 16; ++c) {
            float4 xc = xv[c];
            float4 u0 = w0[c], u1 = w1[c], u2 = w2[c], u3 = w3[c];
            CH4(a0, xc, u0); CH4(a1, xc, u1);
            CH4(a2, xc, u2); CH4(a3, xc, u3);
        }
        float d0 = __fsub_rn(__fadd_rn(A, bn[kb + 0]), __fmul_rn(2.0f, a0));
        float d1 = __fsub_rn(__fadd_rn(A, bn[kb + 1]), __fmul_rn(2.0f, a1));
        float d2 = __fsub_rn(__fadd_rn(A, bn[kb + 2]), __fmul_rn(2.0f, a2));
        float d3 = __fsub_rn(__fadd_rn(A, bn[kb + 3]), __fmul_rn(2.0f, a3));
        if (d0 < bestd) { bestd = d0; besti = kb + 0; }   // ascending k:
        if (d1 < bestd) { bestd = d1; besti = kb + 1; }   // strict < keeps
        if (d2 < bestd) { bestd = d2; besti = kb + 2; }   // first min, like
        if (d3 < bestd) { bestd = d3; besti = kb + 3; }   // np.argmin
    }
    out_idx[n] = (float)besti;
}

// -------------------- gather + STE output + loss partials + segment sums -
__global__ __launch_bounds__(256) void k_quant(
    const float* __restrict__ x, const float* __restrict__ w,
    const float* __restrict__ idxf, float* __restrict__ out0,
    float* __restrict__ sums, int* __restrict__ counts,
    double* __restrict__ lpart) {
    const int gid = blockIdx.x * 256 + threadIdx.x;
    const int n = gid >> 6, d = gid & 63;
    const int idx = (int)idxf[n];
    const float in = x[gid];
    const float q  = w[idx * D_DIM + d];
    out0[gid] = in + (q - in);               // straight-through
    const float diff = in - q;
    atomicAdd(&sums[idx * D_DIM + d], in);
    if (d == 0) atomicAdd(&counts[idx], 1);

    __shared__ double red[256];
    red[threadIdx.x] = (double)diff * (double)diff;
    __syncthreads();
    for (int s = 128; s > 0; s >>= 1) {
        if (threadIdx.x < s) red[threadIdx.x] += red[threadIdx.x + s];
        __syncthreads();
    }
    if (threadIdx.x == 0) lpart[blockIdx.x] = red[0];
}

// -------------------- loss finalize (deterministic) ----------------------
__global__ void k_loss(const double* __restrict__ lpart, float* __restrict__ out1) {
    __shared__ double red[256];
    double s = 0.0;
    for (int i = threadIdx.x; i < 8192; i += 256) s += lpart[i];
    red[threadIdx.x] = s;
    __syncthreads();
    for (int st = 128; st > 0; st >>= 1) {
        if (threadIdx.x < st) red[threadIdx.x] += red[threadIdx.x + st];
        __syncthreads();
    }
    if (threadIdx.x == 0) out1[0] = (float)(0.25 * red[0] / (double)NELEM);
}

// -------------------- ema_cs + partial sums for n ------------------------
__global__ void k_emacs(const float* __restrict__ old_cs, const int* __restrict__ counts,
                        float* __restrict__ out4, double* __restrict__ cspart) {
    const int k = blockIdx.x * 256 + threadIdx.x;
    const float e = 0.99f * old_cs[k] + 0.01f * (float)counts[k];
    out4[k] = e;
    __shared__ double red[256];
    red[threadIdx.x] = (double)e;
    __syncthreads();
    for (int s = 128; s > 0; s >>= 1) {
        if (threadIdx.x < s) red[threadIdx.x] += red[threadIdx.x + s];
        __syncthreads();
    }
    if (threadIdx.x == 0) cspart[blockIdx.x] = red[0];
}

// -------------------- ema_es + new_weight --------------------------------
__global__ __launch_bounds__(256) void k_final(
    const float* __restrict__ old_es, const float* __restrict__ sums,
    const float* __restrict__ out4, const double* __restrict__ cspart,
    float* __restrict__ out3, float* __restrict__ out5) {
    double nd = 0.0;
#pragma unroll
    for (int i = 0; i < 16; ++i) nd += cspart[i];
    const float nf = (float)nd;
    const int gid = blockIdx.x * 256 + threadIdx.x;
    const int k = gid >> 6;
    const float es = 0.99f * old_es[gid] + 0.01f * sums[gid];
    out5[gid] = es;
    const float cs = out4[k];
    const float cssm = (cs + 1e-5f) / (nf + 4096.0f * 1e-5f) * nf;
    out3[gid] = es / cssm;
}

extern "C" void kernel_launch(void* const* d_in, const int* in_sizes, int n_in,
                              void* d_out, int out_size, void* d_ws, size_t ws_size,
                              hipStream_t stream) {
    const float* x      = (const float*)d_in[0];
    const float* w      = (const float*)d_in[1];
    const float* old_cs = (const float*)d_in[2];
    const float* old_es = (const float*)d_in[3];

    float* o    = (float*)d_out;
    float* out0 = o + OUT0_OFF;
    float* out1 = o + OUT1_OFF;
    float* out2 = o + OUT2_OFF;
    float* out3 = o + OUT3_OFF;
    float* out4 = o + OUT4_OFF;
    float* out5 = o + OUT5_OFF;

    char* ws = (char*)d_ws;
    float*  bnorm   = (float*)(ws + WS_BNORM);
    int*    counts  = (int*)(ws + WS_COUNTS);
    float*  sums    = (float*)(ws + WS_SUMS);
    double* lpart   = (double*)(ws + WS_LPART);
    double* cspart  = (double*)(ws + WS_CSPART);

    hipMemsetAsync(counts, 0, K_CODES * sizeof(int), stream);
    hipMemsetAsync(sums, 0, K_CODES * D_DIM * sizeof(float), stream);

    k_bnorm<<<K_CODES / 256, 256, 0, stream>>>(w, bnorm);
    k_score<<<N_VEC / 256, 256, 0, stream>>>(x, w, bnorm, out2);
    k_quant<<<NELEM / 256, 256, 0, stream>>>(x, w, out2, out0, sums, counts, lpart);
    k_loss<<<1, 256, 0, stream>>>(lpart, out1);
    k_emacs<<<K_CODES / 256, 256, 0, stream>>>(old_cs, counts, out4, cspart);
    k_final<<<K_CODES * D_DIM / 256, 256, 0, stream>>>(old_es, sums, out4, cspart,
                                                       out3, out5);
}